// Round 19
// baseline (205.434 us; speedup 1.0000x reference)
//
#include <hip/hip_runtime.h>
#include <math.h>

#define RR 1024
#define BB 16
#define DD 1024
#define K_ACTIVE 20

// clang native vector type for __builtin_nontemporal_store (rejects HIP float4).
typedef float f32x4 __attribute__((ext_vector_type(4)));

// ---------------------------------------------------------------------------
// Kernel 0: PURE WRITER, no dependencies. Zero-fill all of Hs (the ~98%-zeros
// output) with nontemporal stores. Launched first; selected rows are
// overwritten later by nms_gate (only ~1.3 MB). Keeps the 64 MB write out of
// score's read stream AND out of the NMS dependency tail.
// ---------------------------------------------------------------------------
__global__ __launch_bounds__(256) void zero_fill_kernel(float* __restrict__ Hs)
{
    const f32x4 z = (f32x4){0.f, 0.f, 0.f, 0.f};
    f32x4* p = (f32x4*)Hs;
    const int n = RR * BB * DD / 4;                 // 4,194,304 f32x4
    for (int i = blockIdx.x * 256 + threadIdx.x; i < n; i += gridDim.x * 256)
        __builtin_nontemporal_store(z, &p[i]);
}

// ---------------------------------------------------------------------------
// Kernel 1: PURE READER, restructured for MLP. Round-14 data: pure-read score
// still pinned at 2.7 TB/s with VGPR=32 (compiler kept ~2 loads in flight;
// 1/3 of vmem instrs were redundant per-wave w re-reads).
// This version: 2048 persistent blocks; each wave owns TWO pairs (p, p+8192);
// all 20 data loads (2x(H+msg) x 4 + w x 4 = 20 KB/wave) issue back-to-back
// before any use; w loaded ONCE per wave; wave-uniform wid via readfirstlane
// so theta/refr/fb epilogue inputs become early scalar loads; the two
// reduction chains are independent and interleave.
// ---------------------------------------------------------------------------
__global__ __launch_bounds__(256, 4) void score_kernel(
    const float* __restrict__ H, const float* __restrict__ msg,
    const float* __restrict__ w, const float* __restrict__ theta,
    const float* __restrict__ refr, const float* __restrict__ fb,
    float* __restrict__ adj_out)
{
    const int lane = threadIdx.x & 63;
    const int wid  = __builtin_amdgcn_readfirstlane(threadIdx.x >> 6);
    const int p0 = blockIdx.x * 4 + wid;            // 0..8191
    const int p1 = p0 + 8192;                       // 8192..16383
    const int r0 = p0 >> 4, b0 = p0 & 15;
    const int r1 = p1 >> 4, b1 = p1 & 15;

    const float4* W4 = (const float4*)w;
    const float4* H0 = (const float4*)(H   + (size_t)p0 * DD);
    const float4* M0 = (const float4*)(msg + (size_t)p0 * DD);
    const float4* H1 = (const float4*)(H   + (size_t)p1 * DD);
    const float4* M1 = (const float4*)(msg + (size_t)p1 * DD);

    // Issue ALL data loads first: 20 x 16B per lane in flight.
    float4 h0[4], m0v[4], h1[4], m1v[4], ww[4];
#pragma unroll
    for (int k = 0; k < 4; ++k) {
        const int i = lane + 64 * k;                // 256 float4 = 1024 floats
        h0[k]  = H0[i];
        m0v[k] = M0[i];
        h1[k]  = H1[i];
        m1v[k] = M1[i];
        ww[k]  = W4[i];
    }

    // Epilogue scalars early (wave-uniform addresses -> s_load, lgkmcnt).
    const float th0 = theta[r0], rf0 = refr[b0 * RR + r0], f0 = fb[b0 * RR + r0];
    const float th1 = theta[r1], rf1 = refr[b1 * RR + r1], f1 = fb[b1 * RR + r1];

    float dot0 = 0.f, ss0 = 0.f, dot1 = 0.f, ss1 = 0.f;
#pragma unroll
    for (int k = 0; k < 4; ++k) {
        dot0 += h0[k].x * ww[k].x + h0[k].y * ww[k].y + h0[k].z * ww[k].z + h0[k].w * ww[k].w;
        ss0  += m0v[k].x * m0v[k].x + m0v[k].y * m0v[k].y + m0v[k].z * m0v[k].z + m0v[k].w * m0v[k].w;
        dot1 += h1[k].x * ww[k].x + h1[k].y * ww[k].y + h1[k].z * ww[k].z + h1[k].w * ww[k].w;
        ss1  += m1v[k].x * m1v[k].x + m1v[k].y * m1v[k].y + m1v[k].z * m1v[k].z + m1v[k].w * m1v[k].w;
    }
    // wave-64 reductions (4 independent chains, interleaved by scheduler)
#pragma unroll
    for (int off = 32; off > 0; off >>= 1) {
        dot0 += __shfl_down(dot0, off);
        ss0  += __shfl_down(ss0, off);
        dot1 += __shfl_down(dot1, off);
        ss1  += __shfl_down(ss1, off);
    }
    if (lane == 0) {
        const float fbn0 = 0.9f * f0 + 0.1f * sqrtf(ss0);
        adj_out[b0 * RR + r0] = dot0 - th0 - rf0 - 0.5f * fbn0;
        const float fbn1 = 0.9f * f1 + 0.1f * sqrtf(ss1);
        adj_out[b1 * RR + r1] = dot1 - th1 - rf1 - 0.5f * fbn1;
    }
}

// ---------------------------------------------------------------------------
// Kernel 2 (fused NMS + selected-row gate): one block per batch, 256 threads.
// (Round-3 verified version, verbatim.)
//   Wave 0: greedy hex NMS, register-resident (depth-4 argmax tree with
//     tie -> lower index, 6-step shfl_xor butterfly, bitmask suppression,
//     neighbors from an LDS copy of nbrs). Writes hard[b,:]; deposits the
//     selected region list + count into LDS.
//   Then ALL 256 threads copy the <=20 selected rows H[r,b,:] -> Hs[r,b,:]
//     (one float4 per thread per row). Zeros pre-written by zero_fill_kernel.
// ---------------------------------------------------------------------------
__global__ __launch_bounds__(256) void nms_gate_kernel(
    const float* __restrict__ adj, const int* __restrict__ nbrs,
    const float* __restrict__ H,
    float* __restrict__ hard, float* __restrict__ Hs)
{
    __shared__ int nb_lds[RR * 6];            // 24 KiB
    __shared__ int sel_r[K_ACTIVE];
    __shared__ int nsel_lds;

    const int b = blockIdx.x;
    const int tid = threadIdx.x;
    const int lane = tid & 63;
    const int wave = tid >> 6;

    // Preload neighbor table: 6144 ints = 1536 int4, 6 int4 per thread.
    {
        const int4* nb4 = (const int4*)nbrs;
        int4* nl4 = (int4*)nb_lds;
#pragma unroll
        for (int j = 0; j < 6; ++j)
            nl4[tid + 256 * j] = nb4[tid + 256 * j];
    }
    __syncthreads();

    if (wave == 0) {
        float v[16];
#pragma unroll
        for (int j = 0; j < 16; ++j)
            v[j] = adj[b * RR + lane + 64 * j];

        unsigned int sel = 0u;    // bit j: region lane+64j selected
        unsigned int dead = 0u;   // bit j: region lane+64j suppressed/selected
        int nsel = 0;

        for (int it = 0; it < K_ACTIVE; ++it) {
            float tv[16]; int ti[16];
#pragma unroll
            for (int j = 0; j < 16; ++j) {
                tv[j] = ((dead >> j) & 1u) ? -INFINITY : v[j];
                ti[j] = lane + 64 * j;
            }
#pragma unroll
            for (int s = 8; s >= 1; s >>= 1) {
#pragma unroll
                for (int j = 0; j < 8; ++j) {
                    if (j < s) {
                        if (tv[j + s] > tv[j]) { tv[j] = tv[j + s]; ti[j] = ti[j + s]; }
                    }
                }
            }
            float m = tv[0];
            int mi = ti[0];

#pragma unroll
            for (int off = 32; off > 0; off >>= 1) {
                const float ov = __shfl_xor(m, off);
                const int   oi = __shfl_xor(mi, off);
                if (ov > m || (ov == m && oi < mi)) { m = ov; mi = oi; }
            }

            if (m == -INFINITY) break;   // parity with reference exhaustion

            if (lane == 0) sel_r[nsel] = mi;
            nsel++;

            int sup[7];
            sup[0] = mi;
            const int base = mi * 6;
#pragma unroll
            for (int k = 0; k < 6; ++k) sup[k + 1] = nb_lds[base + k];  // broadcast

            sel |= ((mi & 63) == lane) ? (1u << (mi >> 6)) : 0u;
#pragma unroll
            for (int k = 0; k < 7; ++k)
                dead |= ((sup[k] & 63) == lane) ? (1u << (sup[k] >> 6)) : 0u;
        }

        if (lane == 0) nsel_lds = nsel;

#pragma unroll
        for (int j = 0; j < 16; ++j)
            hard[b * RR + lane + 64 * j] = ((sel >> j) & 1u) ? 1.0f : 0.0f;
    }
    __syncthreads();

    // All 256 threads: copy selected rows H[r,b,:] -> Hs[r,b,:] (4 KB each).
    const int nsel = nsel_lds;
    for (int s = 0; s < nsel; ++s) {
        const int r = sel_r[s];
        const size_t off = ((size_t)r * BB + b) * DD;
        ((float4*)(Hs + off))[tid] = ((const float4*)(H + off))[tid];
    }
}

extern "C" void kernel_launch(void* const* d_in, const int* in_sizes, int n_in,
                              void* d_out, int out_size, void* d_ws, size_t ws_size,
                              hipStream_t stream) {
    const float* H     = (const float*)d_in[0];   // [R,B,D]
    const float* msg   = (const float*)d_in[1];   // [R,B,D]
    const float* w     = (const float*)d_in[2];   // [D]
    const float* theta = (const float*)d_in[3];   // [R]
    const float* refr  = (const float*)d_in[4];   // [B,R]
    const float* fb    = (const float*)d_in[5];   // [B,R]
    const int*   nbrs  = (const int*)d_in[6];     // [R,6]

    float* out  = (float*)d_out;
    float* Hs   = out;                                   // [R,B,D]
    float* hard = out + (size_t)RR * BB * DD;            // [B,R]
    float* adj  = hard + (size_t)BB * RR;                // [B,R]

    zero_fill_kernel<<<2048, 256, 0, stream>>>(Hs);
    score_kernel<<<2048, 256, 0, stream>>>(H, msg, w, theta, refr, fb, adj);
    nms_gate_kernel<<<BB, 256, 0, stream>>>(adj, nbrs, H, hard, Hs);
}

// Round 22
// 204.806 us; speedup vs baseline: 1.0031x; 1.0031x over previous
//
#include <hip/hip_runtime.h>
#include <math.h>

#define RR 1024
#define BB 16
#define DD 1024
#define K_ACTIVE 20

// clang native vector type for __builtin_nontemporal_store (rejects HIP float4).
typedef float f32x4 __attribute__((ext_vector_type(4)));

// ---------------------------------------------------------------------------
// Kernel 0: PURE WRITER, no dependencies. Zero-fill all of Hs (the ~98%-zeros
// output) with nontemporal stores. (Unchanged from round 14.)
// ---------------------------------------------------------------------------
__global__ __launch_bounds__(256) void zero_fill_kernel(float* __restrict__ Hs)
{
    const f32x4 z = (f32x4){0.f, 0.f, 0.f, 0.f};
    f32x4* p = (f32x4*)Hs;
    const int n = RR * BB * DD / 4;                 // 4,194,304 f32x4
    for (int i = blockIdx.x * 256 + threadIdx.x; i < n; i += gridDim.x * 256)
        __builtin_nontemporal_store(z, &p[i]);
}

// ---------------------------------------------------------------------------
// Kernel 1: PURE READER with FORCED load batching.
// Round-19 post-mortem: despite source-level batching, VGPR=36 - hipcc sank
// every load to its first use (3rd structural variant defeated). This round:
// asm volatile memory fence between the 20-load batch and compute. Loads
// (memory reads) cannot sink across it -> all 80 destination VGPRs must be
// simultaneously live -> real memory-level parallelism.
// ~116 VGPR expected, under the 128 cap of __launch_bounds__(256,4).
// ---------------------------------------------------------------------------
__global__ __launch_bounds__(256, 4) void score_kernel(
    const float* __restrict__ H, const float* __restrict__ msg,
    const float* __restrict__ w, const float* __restrict__ theta,
    const float* __restrict__ refr, const float* __restrict__ fb,
    float* __restrict__ adj_out)
{
    const int lane = threadIdx.x & 63;
    const int wid  = __builtin_amdgcn_readfirstlane(threadIdx.x >> 6);
    const int p0 = blockIdx.x * 4 + wid;            // 0..8191
    const int p1 = p0 + 8192;                       // 8192..16383
    const int r0 = p0 >> 4, b0 = p0 & 15;
    const int r1 = p1 >> 4, b1 = p1 & 15;

    const float4* W4 = (const float4*)w;
    const float4* H0 = (const float4*)(H   + (size_t)p0 * DD);
    const float4* M0 = (const float4*)(msg + (size_t)p0 * DD);
    const float4* H1 = (const float4*)(H   + (size_t)p1 * DD);
    const float4* M1 = (const float4*)(msg + (size_t)p1 * DD);

    // Issue ALL data loads: 20 x 16B per lane.
    float4 h0[4], m0v[4], h1[4], m1v[4], ww[4];
#pragma unroll
    for (int k = 0; k < 4; ++k) {
        const int i = lane + 64 * k;                // 256 float4 = 1024 floats
        h0[k]  = H0[i];
        m0v[k] = M0[i];
        h1[k]  = H1[i];
        m1v[k] = M1[i];
        ww[k]  = W4[i];
    }

    // FENCE: loads cannot sink below; all 20 results live simultaneously.
    asm volatile("" ::: "memory");

    // Epilogue scalars (wave-uniform addresses -> s_load).
    const float th0 = theta[r0], rf0 = refr[b0 * RR + r0], f0 = fb[b0 * RR + r0];
    const float th1 = theta[r1], rf1 = refr[b1 * RR + r1], f1 = fb[b1 * RR + r1];

    float dot0 = 0.f, ss0 = 0.f, dot1 = 0.f, ss1 = 0.f;
#pragma unroll
    for (int k = 0; k < 4; ++k) {
        dot0 += h0[k].x * ww[k].x + h0[k].y * ww[k].y + h0[k].z * ww[k].z + h0[k].w * ww[k].w;
        ss0  += m0v[k].x * m0v[k].x + m0v[k].y * m0v[k].y + m0v[k].z * m0v[k].z + m0v[k].w * m0v[k].w;
        dot1 += h1[k].x * ww[k].x + h1[k].y * ww[k].y + h1[k].z * ww[k].z + h1[k].w * ww[k].w;
        ss1  += m1v[k].x * m1v[k].x + m1v[k].y * m1v[k].y + m1v[k].z * m1v[k].z + m1v[k].w * m1v[k].w;
    }
    // wave-64 reductions (4 independent chains, interleaved by scheduler)
#pragma unroll
    for (int off = 32; off > 0; off >>= 1) {
        dot0 += __shfl_down(dot0, off);
        ss0  += __shfl_down(ss0, off);
        dot1 += __shfl_down(dot1, off);
        ss1  += __shfl_down(ss1, off);
    }
    if (lane == 0) {
        const float fbn0 = 0.9f * f0 + 0.1f * sqrtf(ss0);
        adj_out[b0 * RR + r0] = dot0 - th0 - rf0 - 0.5f * fbn0;
        const float fbn1 = 0.9f * f1 + 0.1f * sqrtf(ss1);
        adj_out[b1 * RR + r1] = dot1 - th1 - rf1 - 0.5f * fbn1;
    }
}

// ---------------------------------------------------------------------------
// Kernel 2 (fused NMS + selected-row gate): one block per batch, 256 threads.
// (Round-3 verified version, verbatim.)
// ---------------------------------------------------------------------------
__global__ __launch_bounds__(256) void nms_gate_kernel(
    const float* __restrict__ adj, const int* __restrict__ nbrs,
    const float* __restrict__ H,
    float* __restrict__ hard, float* __restrict__ Hs)
{
    __shared__ int nb_lds[RR * 6];            // 24 KiB
    __shared__ int sel_r[K_ACTIVE];
    __shared__ int nsel_lds;

    const int b = blockIdx.x;
    const int tid = threadIdx.x;
    const int lane = tid & 63;
    const int wave = tid >> 6;

    // Preload neighbor table: 6144 ints = 1536 int4, 6 int4 per thread.
    {
        const int4* nb4 = (const int4*)nbrs;
        int4* nl4 = (int4*)nb_lds;
#pragma unroll
        for (int j = 0; j < 6; ++j)
            nl4[tid + 256 * j] = nb4[tid + 256 * j];
    }
    __syncthreads();

    if (wave == 0) {
        float v[16];
#pragma unroll
        for (int j = 0; j < 16; ++j)
            v[j] = adj[b * RR + lane + 64 * j];

        unsigned int sel = 0u;    // bit j: region lane+64j selected
        unsigned int dead = 0u;   // bit j: region lane+64j suppressed/selected
        int nsel = 0;

        for (int it = 0; it < K_ACTIVE; ++it) {
            float tv[16]; int ti[16];
#pragma unroll
            for (int j = 0; j < 16; ++j) {
                tv[j] = ((dead >> j) & 1u) ? -INFINITY : v[j];
                ti[j] = lane + 64 * j;
            }
#pragma unroll
            for (int s = 8; s >= 1; s >>= 1) {
#pragma unroll
                for (int j = 0; j < 8; ++j) {
                    if (j < s) {
                        if (tv[j + s] > tv[j]) { tv[j] = tv[j + s]; ti[j] = ti[j + s]; }
                    }
                }
            }
            float m = tv[0];
            int mi = ti[0];

#pragma unroll
            for (int off = 32; off > 0; off >>= 1) {
                const float ov = __shfl_xor(m, off);
                const int   oi = __shfl_xor(mi, off);
                if (ov > m || (ov == m && oi < mi)) { m = ov; mi = oi; }
            }

            if (m == -INFINITY) break;   // parity with reference exhaustion

            if (lane == 0) sel_r[nsel] = mi;
            nsel++;

            int sup[7];
            sup[0] = mi;
            const int base = mi * 6;
#pragma unroll
            for (int k = 0; k < 6; ++k) sup[k + 1] = nb_lds[base + k];  // broadcast

            sel |= ((mi & 63) == lane) ? (1u << (mi >> 6)) : 0u;
#pragma unroll
            for (int k = 0; k < 7; ++k)
                dead |= ((sup[k] & 63) == lane) ? (1u << (sup[k] >> 6)) : 0u;
        }

        if (lane == 0) nsel_lds = nsel;

#pragma unroll
        for (int j = 0; j < 16; ++j)
            hard[b * RR + lane + 64 * j] = ((sel >> j) & 1u) ? 1.0f : 0.0f;
    }
    __syncthreads();

    // All 256 threads: copy selected rows H[r,b,:] -> Hs[r,b,:] (4 KB each).
    const int nsel = nsel_lds;
    for (int s = 0; s < nsel; ++s) {
        const int r = sel_r[s];
        const size_t off = ((size_t)r * BB + b) * DD;
        ((float4*)(Hs + off))[tid] = ((const float4*)(H + off))[tid];
    }
}

extern "C" void kernel_launch(void* const* d_in, const int* in_sizes, int n_in,
                              void* d_out, int out_size, void* d_ws, size_t ws_size,
                              hipStream_t stream) {
    const float* H     = (const float*)d_in[0];   // [R,B,D]
    const float* msg   = (const float*)d_in[1];   // [R,B,D]
    const float* w     = (const float*)d_in[2];   // [D]
    const float* theta = (const float*)d_in[3];   // [R]
    const float* refr  = (const float*)d_in[4];   // [B,R]
    const float* fb    = (const float*)d_in[5];   // [B,R]
    const int*   nbrs  = (const int*)d_in[6];     // [R,6]

    float* out  = (float*)d_out;
    float* Hs   = out;                                   // [R,B,D]
    float* hard = out + (size_t)RR * BB * DD;            // [B,R]
    float* adj  = hard + (size_t)BB * RR;                // [B,R]

    zero_fill_kernel<<<2048, 256, 0, stream>>>(Hs);
    score_kernel<<<2048, 256, 0, stream>>>(H, msg, w, theta, refr, fb, adj);
    nms_gate_kernel<<<BB, 256, 0, stream>>>(adj, nbrs, H, hard, Hs);
}